// Round 1
// baseline (7406.659 us; speedup 1.0000x reference)
//
#include <hip/hip_runtime.h>

// Attention: B=2, H=16, S=2048, D=64, fp32 in/out.
// out = softmax(where(mask, clip(QK^T/8, 1e-9, 1e9), -1e9)) @ V
// d_out = [out (B,H,S,D) | p_attn (B,H,S,S)] fp32.

#define B_ 2
#define H_ 16
#define S_ 2048
#define D_ 64
#define TQ 8        // q rows per block
#define NQT (S_ / TQ)   // 256 q-tiles per (b,h)

__global__ __launch_bounds__(256, 2) void attn_kernel(
    const float* __restrict__ Q, const float* __restrict__ K,
    const float* __restrict__ V, const int* __restrict__ M,
    float* __restrict__ Out, float* __restrict__ P)
{
    const int tid  = threadIdx.x;
    const int lane = tid & 31;   // position within q-group (32 threads per q row)
    const int qq   = tid >> 5;   // local q row 0..7
    const int bid  = blockIdx.x;
    const int bh   = bid / NQT;          // 0..31
    const int qt   = bid % NQT;          // q tile
    const int b    = bh >> 4;            // H=16
    const int qg   = qt * TQ + qq;       // global q row within (b,h)

    const float4* Qrow = reinterpret_cast<const float4*>(Q + ((size_t)bh * S_ + qg) * D_);
    const float4* K4   = reinterpret_cast<const float4*>(K + (size_t)bh * S_ * D_);
    const float4* V4   = reinterpret_cast<const float4*>(V + (size_t)bh * S_ * D_);
    const int*    Mrow = M + ((size_t)b * S_ + qg) * S_;   // mask shape (B,1,S,S)
    float*        Prow = P + ((size_t)bh * S_ + qg) * S_;

    // ---- load q row into registers (same row for all 32 lanes of the group) ----
    float4 qr[16];
#pragma unroll
    for (int j = 0; j < 16; ++j) qr[j] = Qrow[j];

    // ---- QK^T: this thread owns k = kt*256 + lane*8 + i  (64 scores) ----
    float sc[64];
#pragma unroll
    for (int kt = 0; kt < 8; ++kt) {
#pragma unroll
        for (int i = 0; i < 8; ++i) {
            const int k = kt * 256 + lane * 8 + i;
            const float4* Krow = K4 + (size_t)k * 16;
            float ax = 0.f, ay = 0.f, az = 0.f, aw = 0.f;
#pragma unroll
            for (int j = 0; j < 16; ++j) {
                float4 kv = Krow[j];
                ax += kv.x * qr[j].x;
                ay += kv.y * qr[j].y;
                az += kv.z * qr[j].z;
                aw += kv.w * qr[j].w;
            }
            float s = ((ax + ay) + (az + aw)) * 0.125f;
            // clip BEFORE mask, exactly like the reference
            s = fminf(fmaxf(s, 1e-9f), 1e9f);
            sc[kt * 8 + i] = s;
        }
    }

    // ---- apply mask (int32 0/1) ----
#pragma unroll
    for (int kt = 0; kt < 8; ++kt) {
        const int k0 = kt * 256 + lane * 8;
        int4 m0 = *reinterpret_cast<const int4*>(Mrow + k0);
        int4 m1 = *reinterpret_cast<const int4*>(Mrow + k0 + 4);
        if (!m0.x) sc[kt * 8 + 0] = -1e9f;
        if (!m0.y) sc[kt * 8 + 1] = -1e9f;
        if (!m0.z) sc[kt * 8 + 2] = -1e9f;
        if (!m0.w) sc[kt * 8 + 3] = -1e9f;
        if (!m1.x) sc[kt * 8 + 4] = -1e9f;
        if (!m1.y) sc[kt * 8 + 5] = -1e9f;
        if (!m1.z) sc[kt * 8 + 6] = -1e9f;
        if (!m1.w) sc[kt * 8 + 7] = -1e9f;
    }

    // ---- softmax across the 32 lanes of this q-group ----
    float mx = -3.0e38f;
#pragma unroll
    for (int r = 0; r < 64; ++r) mx = fmaxf(mx, sc[r]);
#pragma unroll
    for (int d = 16; d >= 1; d >>= 1) mx = fmaxf(mx, __shfl_xor(mx, d));

    float l = 0.f;
#pragma unroll
    for (int r = 0; r < 64; ++r) { sc[r] = __expf(sc[r] - mx); l += sc[r]; }
#pragma unroll
    for (int d = 16; d >= 1; d >>= 1) l += __shfl_xor(l, d);

    const float inv = 1.0f / l;
#pragma unroll
    for (int r = 0; r < 64; ++r) sc[r] *= inv;

    // ---- write p_attn (coalesced: half-wave covers 2 KB contiguous) ----
#pragma unroll
    for (int kt = 0; kt < 8; ++kt) {
        float4 w0 = make_float4(sc[kt * 8 + 0], sc[kt * 8 + 1], sc[kt * 8 + 2], sc[kt * 8 + 3]);
        float4 w1 = make_float4(sc[kt * 8 + 4], sc[kt * 8 + 5], sc[kt * 8 + 6], sc[kt * 8 + 7]);
        float4* wp = reinterpret_cast<float4*>(Prow + kt * 256 + lane * 8);
        wp[0] = w0;
        wp[1] = w1;
    }

    // ---- PV: partial out over this thread's 64 k's ----
    float4 o[16];
#pragma unroll
    for (int j = 0; j < 16; ++j) o[j] = make_float4(0.f, 0.f, 0.f, 0.f);

#pragma unroll
    for (int kt = 0; kt < 8; ++kt) {
#pragma unroll
        for (int i = 0; i < 8; ++i) {
            const float pw = sc[kt * 8 + i];
            const float4* Vrow = V4 + (size_t)(kt * 256 + lane * 8 + i) * 16;
#pragma unroll
            for (int j = 0; j < 16; ++j) {
                float4 vv = Vrow[j];
                o[j].x += pw * vv.x;
                o[j].y += pw * vv.y;
                o[j].z += pw * vv.z;
                o[j].w += pw * vv.w;
            }
        }
    }

    // ---- butterfly-reduce the 32 partials of each q-group ----
#pragma unroll
    for (int d = 16; d >= 1; d >>= 1) {
#pragma unroll
        for (int j = 0; j < 16; ++j) {
            o[j].x += __shfl_xor(o[j].x, d);
            o[j].y += __shfl_xor(o[j].y, d);
            o[j].z += __shfl_xor(o[j].z, d);
            o[j].w += __shfl_xor(o[j].w, d);
        }
    }

    if (lane == 0) {
        float4* Orow = reinterpret_cast<float4*>(Out + ((size_t)bh * S_ + qg) * D_);
#pragma unroll
        for (int j = 0; j < 16; ++j) Orow[j] = o[j];
    }
}

extern "C" void kernel_launch(void* const* d_in, const int* in_sizes, int n_in,
                              void* d_out, int out_size, void* d_ws, size_t ws_size,
                              hipStream_t stream) {
    const float* Q = (const float*)d_in[0];
    const float* K = (const float*)d_in[1];
    const float* V = (const float*)d_in[2];
    const int*   M = (const int*)d_in[3];

    float* Out = (float*)d_out;
    float* P   = (float*)d_out + (size_t)B_ * H_ * S_ * D_;

    dim3 grid(B_ * H_ * NQT);
    dim3 block(256);
    hipLaunchKernelGGL(attn_kernel, grid, block, 0, stream, Q, K, V, M, Out, P);
}

// Round 2
// 2878.860 us; speedup vs baseline: 2.5728x; 2.5728x over previous
//
#include <hip/hip_runtime.h>

// Attention: B=2, H=16, S=2048, D=64, fp32 in/out.
// out = softmax(where(mask, clip(QK^T/8, 1e-9, 1e9), -1e9)) @ V
// d_out = [out (B,H,S,D) | p_attn (B,H,S,S)] fp32.

#define B_ 2
#define H_ 16
#define S_ 2048
#define D_ 64
#define TQ 8            // q rows per block
#define NQT (S_ / TQ)   // 256 q-tiles per (b,h)
#define KT 128          // k rows per LDS tile
#define NKT (S_ / KT)   // 16 tiles

__global__ __launch_bounds__(256, 2) void attn_kernel(
    const float* __restrict__ Q, const float* __restrict__ K,
    const float* __restrict__ V, const int* __restrict__ M,
    float* __restrict__ Out, float* __restrict__ P)
{
    // 128 rows x 16 float4, XOR-swizzled: logical (row,c) lives at row*16 + (c ^ (row&15))
    __shared__ float4 tile[KT * 16];   // 32 KB

    const int tid  = threadIdx.x;
    const int lane = tid & 31;   // 32 lanes per q-row
    const int qq   = tid >> 5;   // local q row 0..7
    const int bh   = blockIdx.x / NQT;
    const int qt   = blockIdx.x % NQT;
    const int b    = bh >> 4;    // H = 16
    const int qg   = qt * TQ + qq;

    const float4* __restrict__ Qrow = reinterpret_cast<const float4*>(Q + ((size_t)bh * S_ + qg) * D_);
    const float4* __restrict__ K4   = reinterpret_cast<const float4*>(K + (size_t)bh * S_ * D_);
    const float4* __restrict__ V4   = reinterpret_cast<const float4*>(V + (size_t)bh * S_ * D_);
    const int*    __restrict__ Mrow = M + ((size_t)b * S_ + qg) * S_;   // mask is (B,1,S,S)
    float*        __restrict__ Prow = P + ((size_t)bh * S_ + qg) * S_;

    // q row in registers (broadcast across the 32 lanes of the group)
    float4 qr[16];
#pragma unroll
    for (int c = 0; c < 16; ++c) qr[c] = Qrow[c];

    // this thread's 64 scores: k = t*128 + j*32 + lane  ->  sc[t*4 + j]
    float sc[64];

    // ================= QK^T =================
#pragma unroll
    for (int t = 0; t < NKT; ++t) {
        __syncthreads();   // protect previous tile use
        const float4* src = K4 + (size_t)t * (KT * 16);
#pragma unroll
        for (int it = 0; it < 8; ++it) {
            const int f   = it * 256 + tid;      // coalesced: consecutive tid -> consecutive float4
            const int row = f >> 4;
            const int c   = f & 15;
            tile[row * 16 + (c ^ (row & 15))] = src[f];
        }
        __syncthreads();
#pragma unroll
        for (int j = 0; j < 4; ++j) {
            const int r = j * 32 + lane;
            float ax = 0.f, ay = 0.f, az = 0.f, aw = 0.f;
#pragma unroll
            for (int c = 0; c < 16; ++c) {
                const float4 kv = tile[r * 16 + (c ^ (r & 15))];
                ax += kv.x * qr[c].x;
                ay += kv.y * qr[c].y;
                az += kv.z * qr[c].z;
                aw += kv.w * qr[c].w;
            }
            float s = ((ax + ay) + (az + aw)) * 0.125f;
            s = fminf(fmaxf(s, 1e-9f), 1e9f);               // clip BEFORE mask (reference order)
            if (!Mrow[t * KT + j * 32 + lane]) s = -1e9f;   // coalesced int32 load
            sc[t * 4 + j] = s;
        }
    }

    // ================= softmax across the 32 lanes of this q-group =================
    float mx = -3.0e38f;
#pragma unroll
    for (int r = 0; r < 64; ++r) mx = fmaxf(mx, sc[r]);
#pragma unroll
    for (int d = 16; d >= 1; d >>= 1) mx = fmaxf(mx, __shfl_xor(mx, d));

    float l = 0.f;
#pragma unroll
    for (int r = 0; r < 64; ++r) { sc[r] = __expf(sc[r] - mx); l += sc[r]; }
#pragma unroll
    for (int d = 16; d >= 1; d >>= 1) l += __shfl_xor(l, d);

    const float inv = 1.0f / l;
#pragma unroll
    for (int r = 0; r < 64; ++r) sc[r] *= inv;

    // ================= write p_attn (coalesced b32: lanes cover 128B lines) =================
#pragma unroll
    for (int t = 0; t < NKT; ++t)
#pragma unroll
        for (int j = 0; j < 4; ++j)
            Prow[t * KT + j * 32 + lane] = sc[t * 4 + j];

    // ================= PV =================
    float4 o[16];
#pragma unroll
    for (int c = 0; c < 16; ++c) o[c] = make_float4(0.f, 0.f, 0.f, 0.f);

#pragma unroll
    for (int t = 0; t < NKT; ++t) {
        __syncthreads();
        const float4* src = V4 + (size_t)t * (KT * 16);
#pragma unroll
        for (int it = 0; it < 8; ++it) {
            const int f   = it * 256 + tid;
            const int row = f >> 4;
            const int c   = f & 15;
            tile[row * 16 + (c ^ (row & 15))] = src[f];
        }
        __syncthreads();
#pragma unroll
        for (int j = 0; j < 4; ++j) {
            const float pw = sc[t * 4 + j];
            const int r = j * 32 + lane;
#pragma unroll
            for (int c = 0; c < 16; ++c) {
                const float4 vv = tile[r * 16 + (c ^ (r & 15))];
                o[c].x += pw * vv.x;
                o[c].y += pw * vv.y;
                o[c].z += pw * vv.z;
                o[c].w += pw * vv.w;
            }
        }
    }

    // butterfly-reduce the 32 partials of each q-group
#pragma unroll
    for (int d = 16; d >= 1; d >>= 1) {
#pragma unroll
        for (int c = 0; c < 16; ++c) {
            o[c].x += __shfl_xor(o[c].x, d);
            o[c].y += __shfl_xor(o[c].y, d);
            o[c].z += __shfl_xor(o[c].z, d);
            o[c].w += __shfl_xor(o[c].w, d);
        }
    }

    if (lane == 0) {
        float4* Orow = reinterpret_cast<float4*>(Out + ((size_t)bh * S_ + qg) * D_);
#pragma unroll
        for (int c = 0; c < 16; ++c) Orow[c] = o[c];
    }
}

extern "C" void kernel_launch(void* const* d_in, const int* in_sizes, int n_in,
                              void* d_out, int out_size, void* d_ws, size_t ws_size,
                              hipStream_t stream) {
    const float* Q = (const float*)d_in[0];
    const float* K = (const float*)d_in[1];
    const float* V = (const float*)d_in[2];
    const int*   M = (const int*)d_in[3];

    float* Out = (float*)d_out;
    float* P   = (float*)d_out + (size_t)B_ * H_ * S_ * D_;

    dim3 grid(B_ * H_ * NQT);
    dim3 block(256);
    hipLaunchKernelGGL(attn_kernel, grid, block, 0, stream, Q, K, V, M, Out, P);
}

// Round 3
// 599.662 us; speedup vs baseline: 12.3514x; 4.8008x over previous
//
#include <hip/hip_runtime.h>

// Attention B=2,H=16,S=2048,D=64 fp32; out = softmax(mask(clip(QK^T/8)))V
// d_out = [out | p_attn] fp32. MFMA bf16 path, 2-pass (sum, then normalize+PV).

#define B_ 2
#define H_ 16
#define S_ 2048
#define D_ 64
#define BQ 64            // q rows per block
#define NQT (S_ / BQ)    // 32 q tiles per (b,h)
#define NCH (S_ / 64)    // 32 k-chunks of 64

typedef __attribute__((ext_vector_type(8))) short bf16x8;
typedef __attribute__((ext_vector_type(4))) float f32x4;

__device__ inline short f2bf(float f) {
    unsigned u = __float_as_uint(f);
    u = (u + 0x7FFFu + ((u >> 16) & 1u)) >> 16;   // RNE
    return (short)u;
}

// stage a [64 rows][64 f32] global tile -> bf16 LDS row-major, 16B-granule XOR swizzle
__device__ inline void stage64(const float* __restrict__ src, short* dst, int tid) {
#pragma unroll
    for (int it = 0; it < 2; ++it) {
        const int g = it * 256 + tid;      // granule 0..511
        const int row = g >> 3, b = g & 7;
        const float4* s4 = reinterpret_cast<const float4*>(src + row * 64 + b * 8);
        float4 a = s4[0], c = s4[1];
        bf16x8 v;
        v[0]=f2bf(a.x); v[1]=f2bf(a.y); v[2]=f2bf(a.z); v[3]=f2bf(a.w);
        v[4]=f2bf(c.x); v[5]=f2bf(c.y); v[6]=f2bf(c.z); v[7]=f2bf(c.w);
        *reinterpret_cast<bf16x8*>(&dst[row * 64 + ((b ^ (row & 7)) << 3)]) = v;
    }
}

// stage V [64 k][64 d] -> LDS transposed d-major [64 d][64 k] bf16, swizzled
__device__ inline void stageV(const float* __restrict__ src, short* dst, int tid) {
#pragma unroll
    for (int it = 0; it < 2; ++it) {
        const int g = it * 256 + tid;
        const int k = g >> 3, b = g & 7;
        const float4* s4 = reinterpret_cast<const float4*>(src + k * 64 + b * 8);
        float4 a = s4[0], c = s4[1];
        float vals[8] = {a.x, a.y, a.z, a.w, c.x, c.y, c.z, c.w};
#pragma unroll
        for (int i = 0; i < 8; ++i) {
            const int d = b * 8 + i;
            dst[d * 64 + (((k >> 3) ^ (d & 7)) << 3) + (k & 7)] = f2bf(vals[i]);
        }
    }
}

__global__ __launch_bounds__(256, 3) void attn_kernel(
    const float* __restrict__ Q, const float* __restrict__ K,
    const float* __restrict__ V, const int* __restrict__ M,
    float* __restrict__ Out, float* __restrict__ P)
{
    __shared__ short Qs[64 * 64];            // 8KB
    __shared__ short Ks[64 * 64];            // 8KB
    __shared__ short Vs[64 * 64];            // 8KB (d-major)
    __shared__ short Ps[4][16 * 64];         // 8KB
    __shared__ unsigned long long MB[4][NCH * 4][4];  // 16KB mask ballots

    const int tid  = threadIdx.x;
    const int lane = tid & 63;
    const int wv   = tid >> 6;     // wave 0..3
    const int g16  = lane >> 4;    // 0..3
    const int c16  = lane & 15;
    const int rsw  = c16 & 7;

    // XCD-aware swizzle (1024 % 8 == 0, bijective)
    const int wid = (blockIdx.x & 7) * (gridDim.x >> 3) + (blockIdx.x >> 3);
    const int bh = wid >> 5;           // 32 q-tiles per bh
    const int qt = wid & 31;
    const int qbase = qt * BQ;

    const float* Qb = Q + (size_t)bh * S_ * D_;
    const float* Kb = K + (size_t)bh * S_ * D_;
    const float* Vb = V + (size_t)bh * S_ * D_;
    const int*   Mb = M + (size_t)(bh >> 4) * S_ * S_;
    float*       Pg = P + ((size_t)bh * S_ + qbase) * S_;
    float*       Og = Out + ((size_t)bh * S_ + qbase) * D_;

    // ---- stage Q tile, pull this wave's A-fragments into registers ----
    stage64(Qb + (size_t)qbase * D_, Qs, tid);
    __syncthreads();
    const int qrow = wv * 16 + c16;
    const bf16x8 qf0 = *reinterpret_cast<const bf16x8*>(&Qs[qrow * 64 + ((g16 ^ rsw) << 3)]);
    const bf16x8 qf1 = *reinterpret_cast<const bf16x8*>(&Qs[qrow * 64 + (((4 + g16) ^ rsw) << 3)]);

    // =============== PASS A: row sums of exp(masked clipped scores) ===============
    float esum[4] = {0.f, 0.f, 0.f, 0.f};
    for (int ch = 0; ch < NCH; ++ch) {
        __syncthreads();
        stage64(Kb + (size_t)ch * 64 * D_, Ks, tid);
        __syncthreads();
#pragma unroll
        for (int kc = 0; kc < 4; ++kc) {
            const int kr = kc * 16 + c16;
            bf16x8 kf0 = *reinterpret_cast<const bf16x8*>(&Ks[kr * 64 + ((g16 ^ rsw) << 3)]);
            bf16x8 kf1 = *reinterpret_cast<const bf16x8*>(&Ks[kr * 64 + (((4 + g16) ^ rsw) << 3)]);
            f32x4 acc = {0.f, 0.f, 0.f, 0.f};
            acc = __builtin_amdgcn_mfma_f32_16x16x32_bf16(qf0, kf0, acc, 0, 0, 0);
            acc = __builtin_amdgcn_mfma_f32_16x16x32_bf16(qf1, kf1, acc, 0, 0, 0);
            const int kpos = ch * 64 + kc * 16 + c16;
#pragma unroll
            for (int j = 0; j < 4; ++j) {
                const int qr = qbase + wv * 16 + g16 * 4 + j;
                const int mv = Mb[(size_t)qr * S_ + kpos];
                const bool mk = (mv != 0);
                unsigned long long bal = __ballot(mk);
                if (lane == 0) MB[wv][ch * 4 + kc][j] = bal;
                float s = acc[j] * 0.125f;
                s = fminf(fmaxf(s, 1e-9f), 1e9f);
                s = mk ? s : -1e9f;
                esum[j] += __expf(s);
            }
        }
    }

    // reduce row sums across the 16 lanes that share each row
    float inv[4];
#pragma unroll
    for (int j = 0; j < 4; ++j) {
        float v = esum[j];
        v += __shfl_xor(v, 1);
        v += __shfl_xor(v, 2);
        v += __shfl_xor(v, 4);
        v += __shfl_xor(v, 8);
        inv[j] = 1.0f / v;
    }

    // =============== PASS B: recompute, normalize, write p, PV ===============
    f32x4 o[4];
#pragma unroll
    for (int dt = 0; dt < 4; ++dt) o[dt] = f32x4{0.f, 0.f, 0.f, 0.f};

    for (int ch = 0; ch < NCH; ++ch) {
        __syncthreads();
        stage64(Kb + (size_t)ch * 64 * D_, Ks, tid);
        stageV(Vb + (size_t)ch * 64 * D_, Vs, tid);
        __syncthreads();
#pragma unroll
        for (int kc = 0; kc < 4; ++kc) {
            const int kr = kc * 16 + c16;
            bf16x8 kf0 = *reinterpret_cast<const bf16x8*>(&Ks[kr * 64 + ((g16 ^ rsw) << 3)]);
            bf16x8 kf1 = *reinterpret_cast<const bf16x8*>(&Ks[kr * 64 + (((4 + g16) ^ rsw) << 3)]);
            f32x4 acc = {0.f, 0.f, 0.f, 0.f};
            acc = __builtin_amdgcn_mfma_f32_16x16x32_bf16(qf0, kf0, acc, 0, 0, 0);
            acc = __builtin_amdgcn_mfma_f32_16x16x32_bf16(qf1, kf1, acc, 0, 0, 0);
            const int kpos = ch * 64 + kc * 16 + c16;
#pragma unroll
            for (int j = 0; j < 4; ++j) {
                const unsigned long long bal = MB[wv][ch * 4 + kc][j];
                const bool mk = (bal >> lane) & 1ULL;
                float s = acc[j] * 0.125f;
                s = fminf(fmaxf(s, 1e-9f), 1e9f);
                s = mk ? s : -1e9f;
                const float p = __expf(s) * inv[j];
                const int row = g16 * 4 + j;
                Pg[(size_t)(wv * 16 + row) * S_ + kpos] = p;
                const int cg = kc * 16 + c16;
                Ps[wv][row * 64 + ((cg & 7) | ((((cg >> 3)) ^ (row & 7)) << 3))] = f2bf(p);
            }
        }
        // PV over this 64-k chunk (per-wave private Ps; in-wave LDS ordering suffices)
#pragma unroll
        for (int ks = 0; ks < 2; ++ks) {
            bf16x8 pa = *reinterpret_cast<const bf16x8*>(
                &Ps[wv][c16 * 64 + (((ks * 4 + g16) ^ rsw) << 3)]);
#pragma unroll
            for (int dt = 0; dt < 4; ++dt) {
                const int vr = dt * 16 + c16;
                bf16x8 vb = *reinterpret_cast<const bf16x8*>(
                    &Vs[vr * 64 + (((ks * 4 + g16) ^ (vr & 7)) << 3)]);
                o[dt] = __builtin_amdgcn_mfma_f32_16x16x32_bf16(pa, vb, o[dt], 0, 0, 0);
            }
        }
    }

    // ---- write out ----
#pragma unroll
    for (int dt = 0; dt < 4; ++dt)
#pragma unroll
        for (int j = 0; j < 4; ++j)
            Og[(size_t)(wv * 16 + g16 * 4 + j) * D_ + dt * 16 + c16] = o[dt][j];
}

extern "C" void kernel_launch(void* const* d_in, const int* in_sizes, int n_in,
                              void* d_out, int out_size, void* d_ws, size_t ws_size,
                              hipStream_t stream) {
    const float* Q = (const float*)d_in[0];
    const float* K = (const float*)d_in[1];
    const float* V = (const float*)d_in[2];
    const int*   M = (const int*)d_in[3];

    float* Out = (float*)d_out;
    float* P   = (float*)d_out + (size_t)B_ * H_ * S_ * D_;

    dim3 grid(B_ * H_ * NQT);   // 1024
    dim3 block(256);
    hipLaunchKernelGGL(attn_kernel, grid, block, 0, stream, Q, K, V, M, Out, P);
}

// Round 4
// 597.508 us; speedup vs baseline: 12.3959x; 1.0036x over previous
//
#include <hip/hip_runtime.h>

// Attention B=2,H=16,S=2048,D=64 fp32; out = softmax(mask(clip(QK^T/8)))V
// d_out = [out | p_attn] fp32. MFMA bf16 path, 2-pass (sum, then normalize+PV).

#define B_ 2
#define H_ 16
#define S_ 2048
#define D_ 64
#define BQ 64            // q rows per block
#define NQT (S_ / BQ)    // 32 q tiles per (b,h)
#define NCH (S_ / 64)    // 32 k-chunks of 64

typedef __attribute__((ext_vector_type(8))) short bf16x8;
typedef __attribute__((ext_vector_type(4))) float f32x4;

__device__ inline short f2bf(float f) {
    unsigned u = __float_as_uint(f);
    u = (u + 0x7FFFu + ((u >> 16) & 1u)) >> 16;   // RNE
    return (short)u;
}

// stage a [64 rows][64 f32] global tile -> bf16 LDS row-major, 16B-granule XOR swizzle
__device__ inline void stage64(const float* __restrict__ src, short* dst, int tid) {
#pragma unroll
    for (int it = 0; it < 2; ++it) {
        const int g = it * 256 + tid;      // granule 0..511
        const int row = g >> 3, b = g & 7;
        const float4* s4 = reinterpret_cast<const float4*>(src + row * 64 + b * 8);
        float4 a = s4[0], c = s4[1];
        bf16x8 v;
        v[0]=f2bf(a.x); v[1]=f2bf(a.y); v[2]=f2bf(a.z); v[3]=f2bf(a.w);
        v[4]=f2bf(c.x); v[5]=f2bf(c.y); v[6]=f2bf(c.z); v[7]=f2bf(c.w);
        *reinterpret_cast<bf16x8*>(&dst[row * 64 + ((b ^ (row & 7)) << 3)]) = v;
    }
}

// stage V [64 k][64 d] -> LDS transposed d-major [64 d][64 k] bf16, swizzled
__device__ inline void stageV(const float* __restrict__ src, short* dst, int tid) {
#pragma unroll
    for (int it = 0; it < 2; ++it) {
        const int g = it * 256 + tid;
        const int k = g >> 3, b = g & 7;
        const float4* s4 = reinterpret_cast<const float4*>(src + k * 64 + b * 8);
        float4 a = s4[0], c = s4[1];
        float vals[8] = {a.x, a.y, a.z, a.w, c.x, c.y, c.z, c.w};
#pragma unroll
        for (int i = 0; i < 8; ++i) {
            const int d = b * 8 + i;
            dst[d * 64 + (((k >> 3) ^ (d & 7)) << 3) + (k & 7)] = f2bf(vals[i]);
        }
    }
}

__global__ __launch_bounds__(256, 3) void attn_kernel(
    const float* __restrict__ Q, const float* __restrict__ K,
    const float* __restrict__ V, const int* __restrict__ M,
    float* __restrict__ Out, float* __restrict__ P)
{
    __shared__ short Qs[64 * 64];            // 8KB
    __shared__ short Ks[64 * 64];            // 8KB
    __shared__ short Vs[64 * 64];            // 8KB (d-major)
    __shared__ short Ps[4][16 * 64];         // 8KB
    __shared__ unsigned long long MB[4][NCH * 4][4];  // 16KB mask ballots

    const int tid  = threadIdx.x;
    const int lane = tid & 63;
    const int wv   = tid >> 6;     // wave 0..3
    const int g16  = lane >> 4;    // 0..3
    const int c16  = lane & 15;
    const int rsw  = c16 & 7;

    // XCD-aware swizzle (1024 % 8 == 0, bijective)
    const int wid = (blockIdx.x & 7) * (gridDim.x >> 3) + (blockIdx.x >> 3);
    const int bh = wid >> 5;           // 32 q-tiles per bh
    const int qt = wid & 31;
    const int qbase = qt * BQ;

    const float* Qb = Q + (size_t)bh * S_ * D_;
    const float* Kb = K + (size_t)bh * S_ * D_;
    const float* Vb = V + (size_t)bh * S_ * D_;
    const int*   Mb = M + (size_t)(bh >> 4) * S_ * S_;
    float*       Pg = P + ((size_t)bh * S_ + qbase) * S_;
    float*       Og = Out + ((size_t)bh * S_ + qbase) * D_;

    // ---- stage Q tile, pull this wave's A-fragments into registers ----
    stage64(Qb + (size_t)qbase * D_, Qs, tid);
    __syncthreads();
    const int qrow = wv * 16 + c16;
    const bf16x8 qf0 = *reinterpret_cast<const bf16x8*>(&Qs[qrow * 64 + ((g16 ^ rsw) << 3)]);
    const bf16x8 qf1 = *reinterpret_cast<const bf16x8*>(&Qs[qrow * 64 + (((4 + g16) ^ rsw) << 3)]);

    // =============== PASS A: row sums of exp(masked clipped scores) ===============
    float esum[4] = {0.f, 0.f, 0.f, 0.f};
    for (int ch = 0; ch < NCH; ++ch) {
        __syncthreads();
        stage64(Kb + (size_t)ch * 64 * D_, Ks, tid);
        __syncthreads();
#pragma unroll
        for (int kc = 0; kc < 4; ++kc) {
            const int kr = kc * 16 + c16;
            bf16x8 kf0 = *reinterpret_cast<const bf16x8*>(&Ks[kr * 64 + ((g16 ^ rsw) << 3)]);
            bf16x8 kf1 = *reinterpret_cast<const bf16x8*>(&Ks[kr * 64 + (((4 + g16) ^ rsw) << 3)]);
            f32x4 acc = {0.f, 0.f, 0.f, 0.f};
            acc = __builtin_amdgcn_mfma_f32_16x16x32_bf16(qf0, kf0, acc, 0, 0, 0);
            acc = __builtin_amdgcn_mfma_f32_16x16x32_bf16(qf1, kf1, acc, 0, 0, 0);
            const int kpos = ch * 64 + kc * 16 + c16;
#pragma unroll
            for (int j = 0; j < 4; ++j) {
                const int qr = qbase + wv * 16 + g16 * 4 + j;
                const int mv = Mb[(size_t)qr * S_ + kpos];
                const bool mk = (mv != 0);
                unsigned long long bal = __ballot(mk);
                if (lane == 0) MB[wv][ch * 4 + kc][j] = bal;
                float s = acc[j] * 0.125f;
                s = fminf(fmaxf(s, 1e-9f), 1e9f);
                s = mk ? s : -1e9f;
                esum[j] += __expf(s);
            }
        }
    }

    // reduce row sums across the 16 lanes that share each row
    float inv[4];
#pragma unroll
    for (int j = 0; j < 4; ++j) {
        float v = esum[j];
        v += __shfl_xor(v, 1);
        v += __shfl_xor(v, 2);
        v += __shfl_xor(v, 4);
        v += __shfl_xor(v, 8);
        inv[j] = 1.0f / v;
    }

    // =============== PASS B: recompute, normalize, write p, PV ===============
    f32x4 o[4];
#pragma unroll
    for (int dt = 0; dt < 4; ++dt) o[dt] = f32x4{0.f, 0.f, 0.f, 0.f};

    for (int ch = 0; ch < NCH; ++ch) {
        __syncthreads();
        stage64(Kb + (size_t)ch * 64 * D_, Ks, tid);
        stageV(Vb + (size_t)ch * 64 * D_, Vs, tid);
        __syncthreads();
#pragma unroll
        for (int kc = 0; kc < 4; ++kc) {
            const int kr = kc * 16 + c16;
            bf16x8 kf0 = *reinterpret_cast<const bf16x8*>(&Ks[kr * 64 + ((g16 ^ rsw) << 3)]);
            bf16x8 kf1 = *reinterpret_cast<const bf16x8*>(&Ks[kr * 64 + (((4 + g16) ^ rsw) << 3)]);
            f32x4 acc = {0.f, 0.f, 0.f, 0.f};
            acc = __builtin_amdgcn_mfma_f32_16x16x32_bf16(qf0, kf0, acc, 0, 0, 0);
            acc = __builtin_amdgcn_mfma_f32_16x16x32_bf16(qf1, kf1, acc, 0, 0, 0);
            const int kpos = ch * 64 + kc * 16 + c16;
#pragma unroll
            for (int j = 0; j < 4; ++j) {
                const unsigned long long bal = MB[wv][ch * 4 + kc][j];
                const bool mk = (bal >> lane) & 1ULL;
                float s = acc[j] * 0.125f;
                s = fminf(fmaxf(s, 1e-9f), 1e9f);
                s = mk ? s : -1e9f;
                const float p = __expf(s) * inv[j];
                const int row = g16 * 4 + j;
                Pg[(size_t)(wv * 16 + row) * S_ + kpos] = p;
                const int cg = kc * 16 + c16;
                Ps[wv][row * 64 + ((cg & 7) | ((((cg >> 3)) ^ (row & 7)) << 3))] = f2bf(p);
            }
        }
        // PV over this 64-k chunk (per-wave private Ps; in-wave LDS ordering suffices)
#pragma unroll
        for (int ks = 0; ks < 2; ++ks) {
            bf16x8 pa = *reinterpret_cast<const bf16x8*>(
                &Ps[wv][c16 * 64 + (((ks * 4 + g16) ^ rsw) << 3)]);
#pragma unroll
            for (int dt = 0; dt < 4; ++dt) {
                const int vr = dt * 16 + c16;
                bf16x8 vb = *reinterpret_cast<const bf16x8*>(
                    &Vs[vr * 64 + (((ks * 4 + g16) ^ (vr & 7)) << 3)]);
                o[dt] = __builtin_amdgcn_mfma_f32_16x16x32_bf16(pa, vb, o[dt], 0, 0, 0);
            }
        }
    }

    // ---- write out ----
#pragma unroll
    for (int dt = 0; dt < 4; ++dt)
#pragma unroll
        for (int j = 0; j < 4; ++j)
            Og[(size_t)(wv * 16 + g16 * 4 + j) * D_ + dt * 16 + c16] = o[dt][j];
}

extern "C" void kernel_launch(void* const* d_in, const int* in_sizes, int n_in,
                              void* d_out, int out_size, void* d_ws, size_t ws_size,
                              hipStream_t stream) {
    const float* Q = (const float*)d_in[0];
    const float* K = (const float*)d_in[1];
    const float* V = (const float*)d_in[2];
    const int*   M = (const int*)d_in[3];

    float* Out = (float*)d_out;
    float* P   = (float*)d_out + (size_t)B_ * H_ * S_ * D_;

    dim3 grid(B_ * H_ * NQT);   // 1024
    dim3 block(256);
    hipLaunchKernelGGL(attn_kernel, grid, block, 0, stream, Q, K, V, M, Out, P);
}

// Round 5
// 555.149 us; speedup vs baseline: 13.3417x; 1.0763x over previous
//
#include <hip/hip_runtime.h>

// Attention B=2,H=16,S=2048,D=64 fp32; out = softmax(mask(clip(QK^T/8)))V
// d_out = [out | p_attn] fp32. bf16-MFMA, 2-pass (sum, then normalize+PV),
// register-prefetched staging (T14), 32KB LDS -> 4 blocks/CU.

#define B_ 2
#define H_ 16
#define S_ 2048
#define D_ 64
#define BQ 64            // q rows per block
#define NQT (S_ / BQ)    // 32 q tiles per (b,h)
#define NCH (S_ / 64)    // 32 k-chunks of 64

typedef __attribute__((ext_vector_type(8))) short bf16x8;
typedef __attribute__((ext_vector_type(4))) float f32x4;

__device__ inline short f2bf(float f) {
    unsigned u = __float_as_uint(f);
    u = (u + 0x7FFFu + ((u >> 16) & 1u)) >> 16;   // RNE
    return (short)u;
}

// ---- row-major [64][64] bf16 tile (Q / K), 16B-granule XOR swizzle ----
__device__ inline void loadRM(const float* __restrict__ src, int tid, float4* r) {
#pragma unroll
    for (int it = 0; it < 2; ++it) {
        const int g = it * 256 + tid;
        const float4* s4 = reinterpret_cast<const float4*>(src + (g >> 3) * 64 + (g & 7) * 8);
        r[it * 2]     = s4[0];
        r[it * 2 + 1] = s4[1];
    }
}
__device__ inline void writeRM(short* dst, int tid, const float4* r) {
#pragma unroll
    for (int it = 0; it < 2; ++it) {
        const int g = it * 256 + tid;
        const int row = g >> 3, b = g & 7;
        const float4 a = r[it * 2], c = r[it * 2 + 1];
        bf16x8 v;
        v[0]=f2bf(a.x); v[1]=f2bf(a.y); v[2]=f2bf(a.z); v[3]=f2bf(a.w);
        v[4]=f2bf(c.x); v[5]=f2bf(c.y); v[6]=f2bf(c.z); v[7]=f2bf(c.w);
        *reinterpret_cast<bf16x8*>(&dst[row * 64 + ((b ^ (row & 7)) << 3)]) = v;
    }
}

// ---- V tile: d-major [64 d][64 k] bf16, same XOR granule swizzle ----
__device__ inline void loadVc(const float* __restrict__ src, int tid, float* vr) {
    const int d = tid & 63, kq = tid >> 6;
#pragma unroll
    for (int i = 0; i < 16; ++i)
        vr[i] = src[(size_t)(kq * 16 + i) * 64 + d];   // wave covers 256B contiguous per load
}
__device__ inline void writeVc(short* dst, int tid, const float* vr) {
    const int d = tid & 63, kq = tid >> 6;
#pragma unroll
    for (int h = 0; h < 2; ++h) {
        bf16x8 v;
#pragma unroll
        for (int i = 0; i < 8; ++i) v[i] = f2bf(vr[h * 8 + i]);
        *reinterpret_cast<bf16x8*>(&dst[d * 64 + (((2 * kq + h) ^ (d & 7)) << 3)]) = v;
    }
}

__global__ __launch_bounds__(256, 4) void attn_kernel(
    const float* __restrict__ Q, const float* __restrict__ K,
    const float* __restrict__ V, const int* __restrict__ M,
    float* __restrict__ Out, float* __restrict__ P)
{
    __shared__ short Qs[64 * 64];       // 8KB
    __shared__ short Ks[64 * 64];       // 8KB
    __shared__ short Vs[64 * 64];       // 8KB (d-major)
    __shared__ short Ps[4][16 * 64];    // 8KB

    const int tid  = threadIdx.x;
    const int lane = tid & 63;
    const int wv   = tid >> 6;
    const int g16  = lane >> 4;
    const int c16  = lane & 15;
    const int rsw  = c16 & 7;

    // XCD-aware bijective swizzle (1024 % 8 == 0)
    const int wid = (blockIdx.x & 7) * (gridDim.x >> 3) + (blockIdx.x >> 3);
    const int bh = wid >> 5;
    const int qt = wid & 31;
    const int qbase = qt * BQ;

    const float* Qb = Q + ((size_t)bh * S_ + qbase) * D_;
    const float* Kb = K + (size_t)bh * S_ * D_;
    const float* Vb = V + (size_t)bh * S_ * D_;
    const int*   Mb = M + (size_t)(bh >> 4) * S_ * S_;
    float*       Pg = P + ((size_t)bh * S_ + qbase) * S_;
    float*       Og = Out + ((size_t)bh * S_ + qbase) * D_;

    float4 kA[4];
    float  vA[16];

    // ---- prologue: K chunk 0 in flight while Q is staged ----
    loadRM(Kb, tid, kA);
    {
        float4 qA[4];
        loadRM(Qb, tid, qA);
        writeRM(Qs, tid, qA);
    }
    __syncthreads();
    const int qrow = wv * 16 + c16;
    const bf16x8 qf0 = *reinterpret_cast<const bf16x8*>(&Qs[qrow * 64 + ((g16 ^ rsw) << 3)]);
    const bf16x8 qf1 = *reinterpret_cast<const bf16x8*>(&Qs[qrow * 64 + (((4 + g16) ^ rsw) << 3)]);

    const size_t mrow0 = (size_t)(qbase + wv * 16 + g16 * 4) * S_;

    // =============== PASS A: row sums of exp(masked clipped scores) ===============
    float esum[4] = {0.f, 0.f, 0.f, 0.f};
    for (int ch = 0; ch < NCH; ++ch) {
        __syncthreads();                    // previous compute done
        writeRM(Ks, tid, kA);               // regs -> LDS (waits its own vmcnt)
        if (ch + 1 < NCH) loadRM(Kb + (size_t)(ch + 1) * 64 * D_, tid, kA);  // prefetch
        __syncthreads();

        int mv[16];
#pragma unroll
        for (int kc = 0; kc < 4; ++kc)
#pragma unroll
            for (int j = 0; j < 4; ++j)
                mv[kc * 4 + j] = Mb[mrow0 + (size_t)j * S_ + ch * 64 + kc * 16 + c16];

#pragma unroll
        for (int kc = 0; kc < 4; ++kc) {
            const int kr = kc * 16 + c16;
            bf16x8 kf0 = *reinterpret_cast<const bf16x8*>(&Ks[kr * 64 + ((g16 ^ rsw) << 3)]);
            bf16x8 kf1 = *reinterpret_cast<const bf16x8*>(&Ks[kr * 64 + (((4 + g16) ^ rsw) << 3)]);
            f32x4 acc = {0.f, 0.f, 0.f, 0.f};
            acc = __builtin_amdgcn_mfma_f32_16x16x32_bf16(qf0, kf0, acc, 0, 0, 0);
            acc = __builtin_amdgcn_mfma_f32_16x16x32_bf16(qf1, kf1, acc, 0, 0, 0);
#pragma unroll
            for (int j = 0; j < 4; ++j) {
                float s = acc[j] * 0.125f;
                s = fminf(fmaxf(s, 1e-9f), 1e9f);   // clip BEFORE mask (reference order)
                s = mv[kc * 4 + j] ? s : -1e9f;
                esum[j] += __expf(s);
            }
        }
    }

    // pass-B prologue loads first, so the shfl reduce hides their latency
    loadRM(Kb, tid, kA);
    loadVc(Vb, tid, vA);

    float inv[4];
#pragma unroll
    for (int j = 0; j < 4; ++j) {
        float v = esum[j];
        v += __shfl_xor(v, 1);
        v += __shfl_xor(v, 2);
        v += __shfl_xor(v, 4);
        v += __shfl_xor(v, 8);
        inv[j] = 1.0f / v;
    }

    // =============== PASS B: recompute, normalize, write p, PV ===============
    f32x4 o[4];
#pragma unroll
    for (int dt = 0; dt < 4; ++dt) o[dt] = f32x4{0.f, 0.f, 0.f, 0.f};

    for (int ch = 0; ch < NCH; ++ch) {
        __syncthreads();
        writeRM(Ks, tid, kA);
        writeVc(Vs, tid, vA);
        if (ch + 1 < NCH) {
            loadRM(Kb + (size_t)(ch + 1) * 64 * D_, tid, kA);
            loadVc(Vb + (size_t)(ch + 1) * 64 * D_, tid, vA);
        }
        __syncthreads();

        int mv[16];
#pragma unroll
        for (int kc = 0; kc < 4; ++kc)
#pragma unroll
            for (int j = 0; j < 4; ++j)
                mv[kc * 4 + j] = Mb[mrow0 + (size_t)j * S_ + ch * 64 + kc * 16 + c16];

#pragma unroll
        for (int kc = 0; kc < 4; ++kc) {
            const int kr = kc * 16 + c16;
            bf16x8 kf0 = *reinterpret_cast<const bf16x8*>(&Ks[kr * 64 + ((g16 ^ rsw) << 3)]);
            bf16x8 kf1 = *reinterpret_cast<const bf16x8*>(&Ks[kr * 64 + (((4 + g16) ^ rsw) << 3)]);
            f32x4 acc = {0.f, 0.f, 0.f, 0.f};
            acc = __builtin_amdgcn_mfma_f32_16x16x32_bf16(qf0, kf0, acc, 0, 0, 0);
            acc = __builtin_amdgcn_mfma_f32_16x16x32_bf16(qf1, kf1, acc, 0, 0, 0);
            const int kpos = ch * 64 + kc * 16 + c16;
#pragma unroll
            for (int j = 0; j < 4; ++j) {
                float s = acc[j] * 0.125f;
                s = fminf(fmaxf(s, 1e-9f), 1e9f);
                s = mv[kc * 4 + j] ? s : -1e9f;
                const float p = __expf(s) * inv[j];
                const int row = g16 * 4 + j;
                Pg[(size_t)(wv * 16 + row) * S_ + kpos] = p;
                const int cg = kc * 16 + c16;
                Ps[wv][row * 64 + ((cg & 7) | ((((cg >> 3)) ^ (row & 7)) << 3))] = f2bf(p);
            }
        }

        // PV over this 64-k chunk (per-wave private Ps)
#pragma unroll
        for (int ks = 0; ks < 2; ++ks) {
            bf16x8 pa = *reinterpret_cast<const bf16x8*>(
                &Ps[wv][c16 * 64 + (((ks * 4 + g16) ^ rsw) << 3)]);
#pragma unroll
            for (int dt = 0; dt < 4; ++dt) {
                const int vr = dt * 16 + c16;
                bf16x8 vb = *reinterpret_cast<const bf16x8*>(
                    &Vs[vr * 64 + (((ks * 4 + g16) ^ rsw) << 3)]);
                o[dt] = __builtin_amdgcn_mfma_f32_16x16x32_bf16(pa, vb, o[dt], 0, 0, 0);
            }
        }
    }

    // ---- write out ----
#pragma unroll
    for (int dt = 0; dt < 4; ++dt)
#pragma unroll
        for (int j = 0; j < 4; ++j)
            Og[(size_t)(wv * 16 + g16 * 4 + j) * D_ + dt * 16 + c16] = o[dt][j];
}

extern "C" void kernel_launch(void* const* d_in, const int* in_sizes, int n_in,
                              void* d_out, int out_size, void* d_ws, size_t ws_size,
                              hipStream_t stream) {
    const float* Q = (const float*)d_in[0];
    const float* K = (const float*)d_in[1];
    const float* V = (const float*)d_in[2];
    const int*   M = (const int*)d_in[3];

    float* Out = (float*)d_out;
    float* P   = (float*)d_out + (size_t)B_ * H_ * S_ * D_;

    dim3 grid(B_ * H_ * NQT);   // 1024
    dim3 block(256);
    hipLaunchKernelGGL(attn_kernel, grid, block, 0, stream, Q, K, V, M, Out, P);
}